// Round 17
// baseline (265.955 us; speedup 1.0000x reference)
//
#include <hip/hip_runtime.h>

// Depthwise 7x7 true-convolution (flipped kernel, SAME zero pad) + mish,
// via MFMA (v_mfma_f32_16x16x32_f16) with banded-Toeplitz weight matrices.
// Round-17: sliding-ring, full-plane-width tiles.
//  - Block = half plane (128 rows x 256 cols) = 8 tiles of 16 rows x 256 cols.
//    Wave w owns the 64-col strip c0 = 64w (4 MFMA col-subtiles).
//  - Input rows live in a 40-slot ring of full-width f16 rows (PITCH 272:
//    8-half zero pad + 256 data + 8-half zero pad; pads written once ->
//    horizontal SAME padding with ZERO per-granule column checks).
//  - Advance 16 rows/tile; window 22 rows. Read slots (gr in [W-3,W+18]) and
//    write slots (gr in [W+19,W+34]) differ by 1..37 mod 40 -> disjoint, no
//    WAR race; one drain-free barrier per tile orders write -> next read.
//    Each plane row is staged exactly once (vertical halo kept in ring).
//  - Staging is lane-linear: scalar row base + 16B*lane, 4 float4 loads per
//    thread per tile (T14 split kept: raw loads early, cvt+ds_write late).
//  - A-read banks: slot*272 halfs => start bank 8*(lrow&3)+4*lk+const ->
//    uniform 8 words/bank = ds_read_b128 floor.  B aliased into ring.
//
// Math per 16x16 output subtile, kernel row p:
//   C[i,j] += A_p[i,:] x B_p[:,j],  A_p[i,k] = Xf16[W+i+p-3, c0+16t4-8+k],
//   B_p[k,j] = W'[p][k-j-5] (banded), W'[p][q] = kern[6-p][6-q].
// MFMA C layout (m89): col = lane&15, row = (lane>>4)*4 + reg.

#define HW 256
#define RING 40
#define PITCH 272          // halfs per ring row (544 B)
#define TPB 8              // tiles per block (half a plane)

typedef _Float16 f16x8 __attribute__((ext_vector_type(8)));
typedef float    f32x4 __attribute__((ext_vector_type(4)));
typedef __fp16   h2    __attribute__((ext_vector_type(2)));
union U32H2 { unsigned u; h2 h; };
union BFU   { uint4 u; f16x8 h; };

__device__ __forceinline__ float mish_f(float y) {
    float t = __expf(y);            // inf-safe: d -> inf -> 2/d -> 0 -> y*1
    float u = 1.0f + t;
    float d = __fmaf_rn(u, u, 1.0f);
    return y * (1.0f - __fdividef(2.0f, d));
}

__global__ __launch_bounds__(256)
__attribute__((amdgpu_waves_per_eu(6, 8)))
void dwconv7_mish_ring(const float* __restrict__ x,
                       const float* __restrict__ kern,
                       float* __restrict__ out) {
    __shared__ __align__(16) _Float16 ring[RING * PITCH];   // 21,760 B
    unsigned* lds_B = (unsigned*)ring;                      // init-time alias

    const int tid  = threadIdx.x;
    const int lane = tid & 63;
    const int w    = tid >> 6;           // wave -> 64-col strip
    const int lrow = lane & 15;
    const int lk   = lane >> 4;
    const int c0   = w << 6;

    const int bid   = blockIdx.x;
    const int plane = bid >> 1;
    const int r0    = (bid & 1) << 7;    // 0 or 128

    const float* __restrict__ xp = x + (size_t)plane * (HW * HW);
    float* __restrict__ op = out + (size_t)plane * (HW * HW);

    // Flipped kernel in SGPRs: kf[p*7+q] = kern[6-p][6-q]
    float kf[49];
    #pragma unroll
    for (int i = 0; i < 49; ++i) {
        int p = i / 7, q = i - p * 7;
        kf[i] = __int_as_float(__builtin_amdgcn_readfirstlane(
                    __float_as_int(kern[(6 - p) * 7 + (6 - q)])));
    }

    // Banded-Toeplitz B_p[16][32] f16, word idx = p*256 + j*16 + k/2.
    {
        const int j  = tid >> 4;
        const int kw = tid & 15;
        #pragma unroll
        for (int p = 0; p < 7; ++p) {
            const int d0 = 2 * kw - j - 5;
            const int d1 = d0 + 1;
            float v0 = 0.f, v1 = 0.f;
            #pragma unroll
            for (int q = 0; q < 7; ++q) {
                v0 = (d0 == q) ? kf[p * 7 + q] : v0;
                v1 = (d1 == q) ? kf[p * 7 + q] : v1;
            }
            U32H2 u; u.h = __builtin_amdgcn_cvt_pkrtz(v0, v1);
            lds_B[p * 256 + tid] = u.u;
        }
    }
    __syncthreads();

    // B fragments hoisted: B[k=8lk+e, j=lrow], contiguous 16 B per lane.
    f16x8 bfrag[7];
    #pragma unroll
    for (int p = 0; p < 7; ++p) {
        BFU bu;
        bu.u = ((const uint4*)lds_B)[(p << 6) + (lrow << 2) + lk];
        bfrag[p] = bu.h;
    }
    __syncthreads();   // bfrag reads done before ring overwrites the B alias

    // Zero the horizontal pads once: 40 rows x {halfs 0..7, 264..271}.
    if (tid < 160) {
        int row = tid >> 2, q = tid & 3;
        ((uint2*)ring)[row * 68 + (q < 2 ? q : 64 + q)] = make_uint2(0u, 0u);
    }

    // Prologue: stage rows gr = r0-3 .. r0+18 (22 rows; OOB rows -> zeros).
    #pragma unroll
    for (int i = 0; i < 6; ++i) {
        const int row = w + 4 * i;            // wave-uniform
        if (row < 22) {
            const int gr = r0 - 3 + row;
            const int slot = (gr + RING) % RING;
            float4 f = make_float4(0.f, 0.f, 0.f, 0.f);
            if ((unsigned)gr < (unsigned)HW)
                f = *(const float4*)(xp + (gr << 8) + 4 * lane);
            U32H2 a, b;
            a.h = __builtin_amdgcn_cvt_pkrtz(f.x, f.y);
            b.h = __builtin_amdgcn_cvt_pkrtz(f.z, f.w);
            ((uint2*)ring)[slot * 68 + 2 + lane] = make_uint2(a.u, b.u);
        }
    }
    __syncthreads();

    float4 rf[4];

    #pragma unroll 1
    for (int t = 0; t < TPB; ++t) {
        const int W = r0 + (t << 4);          // tile's first output row

        // ---- step 1: issue next tile's RAW loads (rows W+19..W+34) ----
        if (t + 1 < TPB) {
            #pragma unroll
            for (int i = 0; i < 4; ++i) {
                const int gr = W + 19 + w + 4 * i;       // wave-uniform
                rf[i] = make_float4(0.f, 0.f, 0.f, 0.f);
                if (gr < HW)
                    rf[i] = *(const float4*)(xp + (gr << 8) + 4 * lane);
            }
        }
        __builtin_amdgcn_sched_barrier(0);

        // ---- step 2: compute tile (16 rows x 64 cols per wave) ----
        const int b0 = (W + 37) % RING;       // slot of gr = W-3
        int sa[7];                            // per-lane row base (halfs)
        #pragma unroll
        for (int p = 0; p < 7; ++p) {
            int s = b0 + lrow + p;
            s -= (s >= RING) ? RING : 0;
            sa[p] = s * PITCH;
        }
        #pragma unroll
        for (int t4 = 0; t4 < 4; ++t4) {
            f32x4 acc = {0.f, 0.f, 0.f, 0.f};
            #pragma unroll
            for (int p = 0; p < 7; ++p) {
                f16x8 a = *(const f16x8*)(ring + sa[p] + c0 + 16 * t4 + 8 * lk);
                acc = __builtin_amdgcn_mfma_f32_16x16x32_f16(a, bfrag[p], acc,
                                                             0, 0, 0);
            }
            const int col = c0 + 16 * t4 + lrow;
            const int rb  = W + (lk << 2);
            op[(rb + 0) * HW + col] = mish_f(acc[0]);
            op[(rb + 1) * HW + col] = mish_f(acc[1]);
            op[(rb + 2) * HW + col] = mish_f(acc[2]);
            op[(rb + 3) * HW + col] = mish_f(acc[3]);
        }
        __builtin_amdgcn_sched_barrier(0);

        // ---- step 3: consume loads (vmcnt wait lands HERE), cvt, ds_write
        //      (write slots disjoint from this tile's read slots mod 40) ----
        if (t + 1 < TPB) {
            #pragma unroll
            for (int i = 0; i < 4; ++i) {
                const int gr = W + 19 + w + 4 * i;
                const int slot = gr % RING;
                U32H2 a, b;
                a.h = __builtin_amdgcn_cvt_pkrtz(rf[i].x, rf[i].y);
                b.h = __builtin_amdgcn_cvt_pkrtz(rf[i].z, rf[i].w);
                ((uint2*)ring)[slot * 68 + 2 + lane] = make_uint2(a.u, b.u);
            }
        }

        // ---- step 4: drain-free barrier (LDS visibility only) ----
        asm volatile("s_waitcnt lgkmcnt(0)\n\ts_barrier" ::: "memory");
        __builtin_amdgcn_sched_barrier(0);
    }
}

extern "C" void kernel_launch(void* const* d_in, const int* in_sizes, int n_in,
                              void* d_out, int out_size, void* d_ws, size_t ws_size,
                              hipStream_t stream) {
    const float* x = (const float*)d_in[0];
    const float* k = (const float*)d_in[1];
    float* out = (float*)d_out;

    dim3 grid(2 * 16 * 64, 1, 1);   // 2048 blocks: 2 per plane
    dim3 block(256);
    dwconv7_mish_ring<<<grid, block, 0, stream>>>(x, k, out);
}

// Round 18
// 114.708 us; speedup vs baseline: 2.3185x; 2.3185x over previous
//
#include <hip/hip_runtime.h>

// Depthwise 7x7 true-convolution (flipped kernel, SAME zero pad) + mish,
// via MFMA (v_mfma_f32_16x16x32_f16) with banded-Toeplitz weight matrices.
// Round-18 = round-17 sliding-ring with ONE change: waves_per_eu(6,8) ->
// (4,7). R17's (6,8) forced a ~64-VGPR budget on a ~80-VGPR structure ->
// scratch spill (VGPR_Count 40, FETCH +285 MB, WRITE +263 MB, 266us).
// (4,7) = R16's proven no-spill budget.
//
//  - Block = half plane (128 rows x 256 cols) = 8 tiles of 16 rows x 256 cols.
//    Wave w owns the 64-col strip c0 = 64w (4 MFMA col-subtiles).
//  - Input rows in a 40-slot ring of full-width f16 rows (PITCH 272: 8-half
//    zero pad + 256 data + 8-half pad; pads written once -> horizontal SAME
//    padding with zero per-granule column checks).
//  - Advance 16 rows/tile; window 22 rows. Read slots (gr in [W-3,W+18]) vs
//    write slots (gr in [W+19,W+34]): diff 1..37 mod 40 -> disjoint, no WAR
//    race; one drain-free barrier per tile. Each plane row staged once.
//  - Staging lane-linear: scalar row base + 16B*lane, 4 float4 loads per
//    thread per tile (T14 split: raw loads early, cvt+ds_write late).
//  - A-read banks: start bank 8*(lrow&3)+4*lk+const -> uniform 8 words/bank
//    = ds_read_b128 floor. B aliased into ring at init.
//
// Math per 16x16 output subtile, kernel row p:
//   C[i,j] += A_p[i,:] x B_p[:,j],  A_p[i,k] = Xf16[W+i+p-3, c0+16t4-8+k],
//   B_p[k,j] = W'[p][k-j-5] (banded), W'[p][q] = kern[6-p][6-q].
// MFMA C layout (m89): col = lane&15, row = (lane>>4)*4 + reg.

#define HW 256
#define RING 40
#define PITCH 272          // halfs per ring row (544 B)
#define TPB 8              // tiles per block (half a plane)

typedef _Float16 f16x8 __attribute__((ext_vector_type(8)));
typedef float    f32x4 __attribute__((ext_vector_type(4)));
typedef __fp16   h2    __attribute__((ext_vector_type(2)));
union U32H2 { unsigned u; h2 h; };
union BFU   { uint4 u; f16x8 h; };

__device__ __forceinline__ float mish_f(float y) {
    float t = __expf(y);            // inf-safe: d -> inf -> 2/d -> 0 -> y*1
    float u = 1.0f + t;
    float d = __fmaf_rn(u, u, 1.0f);
    return y * (1.0f - __fdividef(2.0f, d));
}

__global__ __launch_bounds__(256)
__attribute__((amdgpu_waves_per_eu(4, 7)))
void dwconv7_mish_ring2(const float* __restrict__ x,
                        const float* __restrict__ kern,
                        float* __restrict__ out) {
    __shared__ __align__(16) _Float16 ring[RING * PITCH];   // 21,760 B
    unsigned* lds_B = (unsigned*)ring;                      // init-time alias

    const int tid  = threadIdx.x;
    const int lane = tid & 63;
    const int w    = tid >> 6;           // wave -> 64-col strip
    const int lrow = lane & 15;
    const int lk   = lane >> 4;
    const int c0   = w << 6;

    const int bid   = blockIdx.x;
    const int plane = bid >> 1;
    const int r0    = (bid & 1) << 7;    // 0 or 128

    const float* __restrict__ xp = x + (size_t)plane * (HW * HW);
    float* __restrict__ op = out + (size_t)plane * (HW * HW);

    // Flipped kernel in SGPRs: kf[p*7+q] = kern[6-p][6-q]
    float kf[49];
    #pragma unroll
    for (int i = 0; i < 49; ++i) {
        int p = i / 7, q = i - p * 7;
        kf[i] = __int_as_float(__builtin_amdgcn_readfirstlane(
                    __float_as_int(kern[(6 - p) * 7 + (6 - q)])));
    }

    // Banded-Toeplitz B_p[16][32] f16, word idx = p*256 + j*16 + k/2.
    {
        const int j  = tid >> 4;
        const int kw = tid & 15;
        #pragma unroll
        for (int p = 0; p < 7; ++p) {
            const int d0 = 2 * kw - j - 5;
            const int d1 = d0 + 1;
            float v0 = 0.f, v1 = 0.f;
            #pragma unroll
            for (int q = 0; q < 7; ++q) {
                v0 = (d0 == q) ? kf[p * 7 + q] : v0;
                v1 = (d1 == q) ? kf[p * 7 + q] : v1;
            }
            U32H2 u; u.h = __builtin_amdgcn_cvt_pkrtz(v0, v1);
            lds_B[p * 256 + tid] = u.u;
        }
    }
    __syncthreads();

    // B fragments hoisted: B[k=8lk+e, j=lrow], contiguous 16 B per lane.
    f16x8 bfrag[7];
    #pragma unroll
    for (int p = 0; p < 7; ++p) {
        BFU bu;
        bu.u = ((const uint4*)lds_B)[(p << 6) + (lrow << 2) + lk];
        bfrag[p] = bu.h;
    }
    __syncthreads();   // bfrag reads done before ring overwrites the B alias

    // Zero the horizontal pads once: 40 rows x {halfs 0..7, 264..271}.
    if (tid < 160) {
        int row = tid >> 2, q = tid & 3;
        ((uint2*)ring)[row * 68 + (q < 2 ? q : 64 + q)] = make_uint2(0u, 0u);
    }

    // Prologue: stage rows gr = r0-3 .. r0+18 (22 rows; OOB rows -> zeros).
    #pragma unroll
    for (int i = 0; i < 6; ++i) {
        const int row = w + 4 * i;            // wave-uniform
        if (row < 22) {
            const int gr = r0 - 3 + row;
            const int slot = (gr + RING) % RING;
            float4 f = make_float4(0.f, 0.f, 0.f, 0.f);
            if ((unsigned)gr < (unsigned)HW)
                f = *(const float4*)(xp + (gr << 8) + 4 * lane);
            U32H2 a, b;
            a.h = __builtin_amdgcn_cvt_pkrtz(f.x, f.y);
            b.h = __builtin_amdgcn_cvt_pkrtz(f.z, f.w);
            ((uint2*)ring)[slot * 68 + 2 + lane] = make_uint2(a.u, b.u);
        }
    }
    __syncthreads();

    float4 rf[4];

    #pragma unroll 1
    for (int t = 0; t < TPB; ++t) {
        const int W = r0 + (t << 4);          // tile's first output row

        // ---- step 1: issue next tile's RAW loads (rows W+19..W+34) ----
        if (t + 1 < TPB) {
            #pragma unroll
            for (int i = 0; i < 4; ++i) {
                const int gr = W + 19 + w + 4 * i;       // wave-uniform
                rf[i] = make_float4(0.f, 0.f, 0.f, 0.f);
                if (gr < HW)
                    rf[i] = *(const float4*)(xp + (gr << 8) + 4 * lane);
            }
        }
        __builtin_amdgcn_sched_barrier(0);

        // ---- step 2: compute tile (16 rows x 64 cols per wave) ----
        const int b0 = (W + 37) % RING;       // slot of gr = W-3
        int sa[7];                            // per-lane row base (halfs)
        #pragma unroll
        for (int p = 0; p < 7; ++p) {
            int s = b0 + lrow + p;
            s -= (s >= RING) ? RING : 0;
            sa[p] = s * PITCH;
        }
        #pragma unroll
        for (int t4 = 0; t4 < 4; ++t4) {
            f32x4 acc = {0.f, 0.f, 0.f, 0.f};
            #pragma unroll
            for (int p = 0; p < 7; ++p) {
                f16x8 a = *(const f16x8*)(ring + sa[p] + c0 + 16 * t4 + 8 * lk);
                acc = __builtin_amdgcn_mfma_f32_16x16x32_f16(a, bfrag[p], acc,
                                                             0, 0, 0);
            }
            const int col = c0 + 16 * t4 + lrow;
            const int rb  = W + (lk << 2);
            op[(rb + 0) * HW + col] = mish_f(acc[0]);
            op[(rb + 1) * HW + col] = mish_f(acc[1]);
            op[(rb + 2) * HW + col] = mish_f(acc[2]);
            op[(rb + 3) * HW + col] = mish_f(acc[3]);
        }
        __builtin_amdgcn_sched_barrier(0);

        // ---- step 3: consume loads (vmcnt wait lands HERE), cvt, ds_write
        //      (write slots disjoint from this tile's read slots mod 40) ----
        if (t + 1 < TPB) {
            #pragma unroll
            for (int i = 0; i < 4; ++i) {
                const int gr = W + 19 + w + 4 * i;
                const int slot = gr % RING;
                U32H2 a, b;
                a.h = __builtin_amdgcn_cvt_pkrtz(rf[i].x, rf[i].y);
                b.h = __builtin_amdgcn_cvt_pkrtz(rf[i].z, rf[i].w);
                ((uint2*)ring)[slot * 68 + 2 + lane] = make_uint2(a.u, b.u);
            }
        }

        // ---- step 4: drain-free barrier (LDS visibility only) ----
        asm volatile("s_waitcnt lgkmcnt(0)\n\ts_barrier" ::: "memory");
        __builtin_amdgcn_sched_barrier(0);
    }
}

extern "C" void kernel_launch(void* const* d_in, const int* in_sizes, int n_in,
                              void* d_out, int out_size, void* d_ws, size_t ws_size,
                              hipStream_t stream) {
    const float* x = (const float*)d_in[0];
    const float* k = (const float*)d_in[1];
    float* out = (float*)d_out;

    dim3 grid(2 * 16 * 64, 1, 1);   // 2048 blocks: 2 per plane
    dim3 block(256);
    dwconv7_mish_ring2<<<grid, block, 0, stream>>>(x, k, out);
}